// Round 4
// baseline (323.024 us; speedup 1.0000x reference)
//
#include <hip/hip_runtime.h>

#define NTOK 4096
#define DIM 1024
#define NE 8
#define NPAIR (NTOK * 2)

typedef __bf16 bf16x8 __attribute__((ext_vector_type(8)));
typedef float floatx4 __attribute__((ext_vector_type(4)));

__device__ __forceinline__ unsigned short f2bf(float f) {
  unsigned u = __float_as_uint(f);
  u = u + 0x7fffu + ((u >> 16) & 1u);
  return (unsigned short)(u >> 16);
}
__device__ __forceinline__ float bf2f(unsigned short h) {
  return __uint_as_float(((unsigned)h) << 16);
}

__device__ __forceinline__ void gld_lds16(const unsigned short* g, unsigned short* l) {
  __builtin_amdgcn_global_load_lds(
      (const __attribute__((address_space(1))) void*)g,
      (__attribute__((address_space(3))) void*)l, 16, 0, 0);
}

// -------- gating + binning fused: one WAVE per token; last block builds schedule -------
// cnt/done are pre-zeroed by cvt1 (prior kernel on the stream). Each wave's lane 0 does
// two atomicAdds (its token's two expert slots) -> bucket/posmap; the last-arriving
// block (done counter) builds the 128-row-tile schedule.
__global__ __launch_bounds__(256) void gate_bin_kernel(
    const float* __restrict__ x, const float* __restrict__ gW,
    const float* __restrict__ gb,
    float* __restrict__ gp_out, float* __restrict__ pairw,
    int* __restrict__ cnt, int* __restrict__ done,
    int* __restrict__ bucket,      // [NE][NTOK]: pair id per within-expert index
    int* __restrict__ posmap,      // [NPAIR]: (e<<16)|idx
    int* __restrict__ base,        // [NE+1]
    int* __restrict__ sched, int* __restrict__ sched_n,
    unsigned short* __restrict__ x_bf)
{
  const int tid = threadIdx.x;
  const int lane = tid & 63;
  const int wid = tid >> 6;
  const int t = blockIdx.x * 4 + wid;

  float4 xv[4];
#pragma unroll
  for (int j = 0; j < 4; j++)
    xv[j] = ((const float4*)(x + (size_t)t * DIM))[lane + 64 * j];

  // bf16 copy of the row (identical f2bf as the packed-A path)
#pragma unroll
  for (int j = 0; j < 4; j++) {
    ushort4 o;
    o.x = f2bf(xv[j].x); o.y = f2bf(xv[j].y);
    o.z = f2bf(xv[j].z); o.w = f2bf(xv[j].w);
    ((ushort4*)(x_bf + (size_t)t * DIM))[lane + 64 * j] = o;
  }

  float p[NE];
#pragma unroll
  for (int e = 0; e < NE; e++) {
    const float4* gwe = (const float4*)(gW + e * DIM);
    float s = 0.f;
#pragma unroll
    for (int j = 0; j < 4; j++) {
      float4 g = gwe[lane + 64 * j];
      s += xv[j].x * g.x + xv[j].y * g.y + xv[j].z * g.z + xv[j].w * g.w;
    }
    p[e] = s;
  }
#pragma unroll
  for (int e = 0; e < NE; e++) {
#pragma unroll
    for (int off = 32; off >= 1; off >>= 1) p[e] += __shfl_xor(p[e], off);
  }

  float m = -1e30f;
#pragma unroll
  for (int e = 0; e < NE; e++) { p[e] += gb[e]; m = fmaxf(m, p[e]); }
  float s = 0.f;
  float pr[NE];
#pragma unroll
  for (int e = 0; e < NE; e++) { pr[e] = __expf(p[e] - m); s += pr[e]; }
  float inv = 1.f / s;
#pragma unroll
  for (int e = 0; e < NE; e++) pr[e] *= inv;

  if (lane < NE) gp_out[(size_t)t * NE + lane] = pr[lane];

  if (lane == 0) {
    int i0 = 0;
#pragma unroll
    for (int e = 1; e < NE; e++) if (pr[e] > pr[i0]) i0 = e;
    int i1 = (i0 == 0) ? 1 : 0;
#pragma unroll
    for (int e = 0; e < NE; e++) if (e != i0 && pr[e] > pr[i1]) i1 = e;
    float d = __expf(pr[i1] - pr[i0]);
    float w0 = 1.f / (1.f + d);
    pairw[t * 2] = w0;
    pairw[t * 2 + 1] = 1.f - w0;
    int idx0 = atomicAdd(&cnt[i0], 1);
    bucket[i0 * NTOK + idx0] = t * 2;
    posmap[t * 2] = (i0 << 16) | idx0;
    int idx1 = atomicAdd(&cnt[i1], 1);
    bucket[i1 * NTOK + idx1] = t * 2 + 1;
    posmap[t * 2 + 1] = (i1 << 16) | idx1;
  }
  __syncthreads();
  if (tid == 0) {
    __threadfence();                             // order cnt adds before done add
    if (atomicAdd(done, 1) == gridDim.x - 1) {   // last block: build schedule
      int b = 0, pos = 0;
      for (int e = 0; e < NE; e++) {
        int c = atomicAdd(&cnt[e], 0);           // device-coherent read
        base[e] = b;
        int tiles = (c + 127) >> 7;
        for (int i = 0; i < tiles; i++) {
          int valid = c - i * 128; if (valid > 128) valid = 128;
          sched[pos++] = (e << 20) | (i << 8) | valid;
        }
        b += c;
      }
      base[NE] = b;
      *sched_n = pos;
    }
  }
}

// ---------------- fp32 -> bf16 weight conversion (one tensor per launch) ---------------
// cnt9 != nullptr (cvt1 only): block 0 zeroes cnt[0..7] + done (contiguous 9 ints),
// completing before gate_bin launches (stream order).
__global__ __launch_bounds__(256) void cvt_kernel(
    const float4* __restrict__ src, ushort4* __restrict__ dst, int* cnt9)
{
  if (cnt9 && blockIdx.x == 0 && threadIdx.x < NE + 1) cnt9[threadIdx.x] = 0;
  const int i = blockIdx.x * 256 + threadIdx.x;
  float4 v = src[i];
  ushort4 o;
  o.x = f2bf(v.x); o.y = f2bf(v.y); o.z = f2bf(v.z); o.w = f2bf(v.w);
  dst[i] = o;
}

// -------- grouped GEMM: 128x128 tile, BK=64, single-buffer, 8 WAVES (512 thr) ---------
// R0's proven m97-style loop at double the wave concurrency: same grid (576), same
// 32 KB LDS (cap 5 blocks/CU >= 2.25 resident), but 18 waves/CU instead of 9 -> higher
// aggregate LDS-fill rate (R0->R2 established rate ~ waves/CU). Per-wave tile 64x32,
// acc[4][2]; staging/fragment/K order bitwise-identical to R0.
// GATHER=1: A rows gathered from x_bf via bucket (gemm1); GATHER=0: packed rows.
template <int RELU, int GATHER>
__global__ __launch_bounds__(512) void ffn_gemm(
    const unsigned short* __restrict__ A,     // GATHER ? x_bf [NTOK][DIM] : packed [NPAIR][DIM]
    const unsigned short* __restrict__ B,     // [NE][DIM][DIM]
    const float* __restrict__ bias,           // [NE][DIM]
    const int* __restrict__ base,
    const int* __restrict__ bucket,
    const int* __restrict__ sched, const int* __restrict__ sched_n,
    unsigned short* __restrict__ Out)         // packed
{
  const int l = blockIdx.x;
  const int xcd = l & 7;
  const int w = l >> 3;
  const int nt = w & 7;
  const int slot = xcd * 9 + (w >> 3);
  if (slot >= *sched_n) return;
  const int se = sched[slot];
  const int e = se >> 20;
  const int mt = (se >> 8) & 0xfff;
  const int valid = se & 255;               // valid rows in this tile (1..128)
  const int arow0 = base[e] + mt * 128;

  __shared__ unsigned short lda[128 * 64];  // 16 KB
  __shared__ unsigned short ldb[128 * 64];  // 16 KB (32 KB total -> 5 blocks/CU cap)

  const int tid = threadIdx.x;
  const int lane = tid & 63;
  const int wid = tid >> 6;                 // 0..7

  const unsigned short* ap[2];
  const unsigned short* bp[2];
#pragma unroll
  for (int j = 0; j < 2; j++) {
    int g = wid * 2 + j;                    // 16 groups x 8 rows = 128 rows
    int row = g * 8 + (lane >> 3);
    int gran = (lane & 7) ^ (row & 7);      // source-side XOR swizzle (0 conflicts)
    if (GATHER) {
      int idx = mt * 128 + row;             // within-expert index
      int ce = base[e + 1] - base[e];       // expert count (>=1 if tile exists)
      if (idx > ce - 1) idx = ce - 1;       // clamp pad rows (masked at store)
      int tok = bucket[e * NTOK + idx] >> 1;
      ap[j] = A + (size_t)tok * DIM + (gran << 3);
    } else {
      int prow = arow0 + row;
      if (prow > NPAIR - 1) prow = NPAIR - 1;
      ap[j] = A + (size_t)prow * DIM + (gran << 3);
    }
    bp[j] = B + ((size_t)e * DIM + nt * 128 + row) * DIM + (gran << 3);
  }

  floatx4 acc[4][2] = {};
  const int wm = (wid & 1) * 64;            // 2 m-waves x 64 rows
  const int wn = (wid >> 1) * 32;           // 4 n-waves x 32 cols
  const int quad = lane >> 4;
  const int cl = lane & 15;
  const int sw = cl & 7;

  for (int k0 = 0; k0 < 16; k0++) {
#pragma unroll
    for (int j = 0; j < 2; j++) {
      gld_lds16(ap[j], &lda[(wid * 2 + j) * 512]);
      gld_lds16(bp[j], &ldb[(wid * 2 + j) * 512]);
      ap[j] += 64;
      bp[j] += 64;
    }
    __syncthreads();
#pragma unroll
    for (int kk = 0; kk < 64; kk += 32) {
      const int gb = (kk >> 3) + quad;
      const int goff = ((gb ^ sw) << 3);
      bf16x8 af[4], bfr[2];
#pragma unroll
      for (int mi = 0; mi < 4; mi++)
        af[mi] = *(const bf16x8*)&lda[(wm + mi * 16 + cl) * 64 + goff];
#pragma unroll
      for (int ni = 0; ni < 2; ni++)
        bfr[ni] = *(const bf16x8*)&ldb[(wn + ni * 16 + cl) * 64 + goff];
#pragma unroll
      for (int mi = 0; mi < 4; mi++)
#pragma unroll
        for (int ni = 0; ni < 2; ni++)
          acc[mi][ni] = __builtin_amdgcn_mfma_f32_16x16x32_bf16(af[mi], bfr[ni], acc[mi][ni], 0, 0, 0);
    }
    if (k0 < 15) __syncthreads();
  }

  // epilogue: C/D layout col=lane&15, row=(lane>>4)*4+reg [m89]; sequential packed store
#pragma unroll
  for (int ni = 0; ni < 2; ni++) {
    int col = nt * 128 + wn + ni * 16 + cl;
    float bval = bias[e * DIM + col];
#pragma unroll
    for (int mi = 0; mi < 4; mi++) {
#pragma unroll
      for (int reg = 0; reg < 4; reg++) {
        int rl = wm + mi * 16 + quad * 4 + reg;
        if (rl < valid) {
          float v = acc[mi][ni][reg] + bval;
          if (RELU) v = fmaxf(v, 0.f);
          Out[(size_t)(arow0 + rl) * DIM + col] = f2bf(v);
        }
      }
    }
  }
}

// ---------------- combine: y[t] = w0*o[p0] + w1*o[p1] (gather via posmap) --------------
__global__ __launch_bounds__(256) void combine_kernel(
    const unsigned short* __restrict__ o, const int* __restrict__ posmap,
    const int* __restrict__ base, const float* __restrict__ pairw,
    float* __restrict__ y)
{
  const int t = blockIdx.x;
  const int tid = threadIdx.x;
  const int pm0 = posmap[t * 2], pm1 = posmap[t * 2 + 1];
  const int p0 = base[pm0 >> 16] + (pm0 & 0xffff);
  const int p1 = base[pm1 >> 16] + (pm1 & 0xffff);
  const float w0 = pairw[t * 2], w1 = pairw[t * 2 + 1];
  ushort4 a = ((const ushort4*)(o + (size_t)p0 * DIM))[tid];
  ushort4 b = ((const ushort4*)(o + (size_t)p1 * DIM))[tid];
  float4 r;
  r.x = w0 * bf2f(a.x) + w1 * bf2f(b.x);
  r.y = w0 * bf2f(a.y) + w1 * bf2f(b.y);
  r.z = w0 * bf2f(a.z) + w1 * bf2f(b.z);
  r.w = w0 * bf2f(a.w) + w1 * bf2f(b.w);
  ((float4*)(y + (size_t)t * DIM))[tid] = r;
}

extern "C" void kernel_launch(void* const* d_in, const int* in_sizes, int n_in,
                              void* d_out, int out_size, void* d_ws, size_t ws_size,
                              hipStream_t stream) {
  const float* x  = (const float*)d_in[0];
  const float* gW = (const float*)d_in[1];
  const float* gb = (const float*)d_in[2];
  const float* w1 = (const float*)d_in[3];
  const float* b1 = (const float*)d_in[4];
  const float* w2 = (const float*)d_in[5];
  const float* b2 = (const float*)d_in[6];
  float* y  = (float*)d_out;
  float* gp = (float*)d_out + (size_t)NTOK * DIM;

  // ws layout (bytes) — peak 48M + ~230K, same validated envelope as R0-R3.
  // Staged aliasing (all kernels in-stream sequential):
  //  region0 [0,16M):   x_bf (8M, gate->gemm1) -> dead after gemm1 -> w2_bf (cvt2)
  //  region1 [16,32M):  h_pack
  //  region2 [32,48M):  w1_bf (gemm1 B)        -> dead after gemm1 -> o_pack (gemm2 out)
  //  [48M,..):  cnt|done|base|sched|sched_n|bucket|pairw|posmap
  char* ws = (char*)d_ws;
  unsigned short* x_bf   = (unsigned short*)(ws);
  unsigned short* w2_bf  = (unsigned short*)(ws);                      // alias, post-gemm1
  unsigned short* h_pack = (unsigned short*)(ws + (size_t)(16u << 20));
  unsigned short* w1_bf  = (unsigned short*)(ws + (size_t)(32u << 20));
  unsigned short* o_pack = (unsigned short*)(ws + (size_t)(32u << 20)); // alias, post-gemm1
  char* tail = ws + (size_t)(48u << 20);
  int*   cnt     = (int*)(tail);                   // 8
  int*   done    = cnt + NE;                       // 1 (contiguous with cnt: cnt9)
  int*   base    = done + 1;                       // 9
  int*   sched   = base + NE + 1;                  // <=256 (128-row tiles: up to 72)
  int*   sched_n = sched + 256;                    // 1
  int*   bucket  = sched_n + 1;                    // NE*NTOK
  float* pairw   = (float*)(bucket + NE * NTOK);   // NPAIR
  int*   posmap  = (int*)(pairw + NPAIR);          // NPAIR

  const int cvt_blocks = (NE * DIM * DIM / 4) / 256;  // 8192
  const int gemm_grid = 576;                           // 8 xcd x 9 slots x 8 nt
  cvt_kernel<<<cvt_blocks, 256, 0, stream>>>((const float4*)w1, (ushort4*)w1_bf, cnt);
  gate_bin_kernel<<<NTOK / 4, 256, 0, stream>>>(x, gW, gb, gp, pairw, cnt, done,
                                                bucket, posmap, base, sched, sched_n, x_bf);
  ffn_gemm<1, 1><<<gemm_grid, 512, 0, stream>>>(x_bf, w1_bf, b1, base, bucket, sched, sched_n, h_pack);
  cvt_kernel<<<cvt_blocks, 256, 0, stream>>>((const float4*)w2, (ushort4*)w2_bf, nullptr);
  ffn_gemm<0, 0><<<gemm_grid, 512, 0, stream>>>(h_pack, w2_bf, b2, base, bucket, sched, sched_n, o_pack);
  combine_kernel<<<NTOK, 256, 0, stream>>>(o_pack, posmap, base, pairw, y);
}

// Round 6
// 222.025 us; speedup vs baseline: 1.4549x; 1.4549x over previous
//
#include <hip/hip_runtime.h>

#define NTOK 4096
#define DIM 1024
#define NE 8
#define NPAIR (NTOK * 2)

typedef __bf16 bf16x8 __attribute__((ext_vector_type(8)));
typedef float floatx4 __attribute__((ext_vector_type(4)));

__device__ __forceinline__ unsigned short f2bf(float f) {
  unsigned u = __float_as_uint(f);
  u = u + 0x7fffu + ((u >> 16) & 1u);
  return (unsigned short)(u >> 16);
}
__device__ __forceinline__ float bf2f(unsigned short h) {
  return __uint_as_float(((unsigned)h) << 16);
}

__device__ __forceinline__ void gld_lds16(const unsigned short* g, unsigned short* l) {
  __builtin_amdgcn_global_load_lds(
      (const __attribute__((address_space(1))) void*)g,
      (__attribute__((address_space(3))) void*)l, 16, 0, 0);
}

// ---------------- gating: one WAVE per token; block 0 zeroes cnt/done ----------------
// Emits x_bf (bf16 cast of x) so gemm1 gathers A directly. R2-proven version.
__global__ __launch_bounds__(256) void gate_kernel(
    const float* __restrict__ x, const float* __restrict__ gW,
    const float* __restrict__ gb,
    float* __restrict__ gp_out, int2* __restrict__ tops,
    float* __restrict__ pairw, int* __restrict__ cnt, int* __restrict__ done,
    unsigned short* __restrict__ x_bf)
{
  const int tid = threadIdx.x;
  if (blockIdx.x == 0) {
    if (tid < NE) cnt[tid] = 0;
    if (tid == NE) *done = 0;
  }
  const int lane = tid & 63;
  const int wid = tid >> 6;
  const int t = blockIdx.x * 4 + wid;

  float4 xv[4];
#pragma unroll
  for (int j = 0; j < 4; j++)
    xv[j] = ((const float4*)(x + (size_t)t * DIM))[lane + 64 * j];

  // bf16 copy of the row (identical f2bf as the packed-A path)
#pragma unroll
  for (int j = 0; j < 4; j++) {
    ushort4 o;
    o.x = f2bf(xv[j].x); o.y = f2bf(xv[j].y);
    o.z = f2bf(xv[j].z); o.w = f2bf(xv[j].w);
    ((ushort4*)(x_bf + (size_t)t * DIM))[lane + 64 * j] = o;
  }

  float p[NE];
#pragma unroll
  for (int e = 0; e < NE; e++) {
    const float4* gwe = (const float4*)(gW + e * DIM);
    float s = 0.f;
#pragma unroll
    for (int j = 0; j < 4; j++) {
      float4 g = gwe[lane + 64 * j];
      s += xv[j].x * g.x + xv[j].y * g.y + xv[j].z * g.z + xv[j].w * g.w;
    }
    p[e] = s;
  }
#pragma unroll
  for (int e = 0; e < NE; e++) {
#pragma unroll
    for (int off = 32; off >= 1; off >>= 1) p[e] += __shfl_xor(p[e], off);
  }

  float m = -1e30f;
#pragma unroll
  for (int e = 0; e < NE; e++) { p[e] += gb[e]; m = fmaxf(m, p[e]); }
  float s = 0.f;
  float pr[NE];
#pragma unroll
  for (int e = 0; e < NE; e++) { pr[e] = __expf(p[e] - m); s += pr[e]; }
  float inv = 1.f / s;
#pragma unroll
  for (int e = 0; e < NE; e++) pr[e] *= inv;

  if (lane < NE) gp_out[(size_t)t * NE + lane] = pr[lane];

  if (lane == 0) {
    int i0 = 0;
#pragma unroll
    for (int e = 1; e < NE; e++) if (pr[e] > pr[i0]) i0 = e;
    int i1 = (i0 == 0) ? 1 : 0;
#pragma unroll
    for (int e = 0; e < NE; e++) if (e != i0 && pr[e] > pr[i1]) i1 = e;
    float d = __expf(pr[i1] - pr[i0]);
    float w0 = 1.f / (1.f + d);
    tops[t] = make_int2(i0, i1);
    pairw[t * 2] = w0;
    pairw[t * 2 + 1] = 1.f - w0;
  }
}

// ------- binning + schedule: wave-aggregated ballot atomics (R2-proven); ---------------
// last block builds the 128-row-tile schedule.
__global__ __launch_bounds__(256) void bin_sched_kernel(
    const int2* __restrict__ tops, int* __restrict__ cnt,
    int* __restrict__ bucket,      // [NE][NTOK]: pair id per within-expert index
    int* __restrict__ posmap,      // [NPAIR]: (e<<16)|idx for each (token,slot)
    int* __restrict__ done, int* __restrict__ base,   // base[9]
    int* __restrict__ sched, int* __restrict__ sched_n)
{
  const int t = blockIdx.x * 256 + threadIdx.x;
  const int lane = threadIdx.x & 63;
  int2 ti = tops[t];
#pragma unroll
  for (int slot = 0; slot < 2; slot++) {
    int e = slot ? ti.y : ti.x;
#pragma unroll
    for (int ex = 0; ex < NE; ex++) {
      bool mine = (e == ex);
      unsigned long long mask = __ballot(mine);
      if (mask) {
        int leader = __ffsll((long long)mask) - 1;
        int total = __popcll(mask);
        int prefix = __popcll(mask & ((1ull << lane) - 1ull));
        int idx = 0;
        if (lane == leader) idx = atomicAdd(&cnt[ex], total);
        idx = __shfl(idx, leader) + prefix;
        if (mine) {
          bucket[ex * NTOK + idx] = t * 2 + slot;
          posmap[t * 2 + slot] = (ex << 16) | idx;
        }
      }
    }
  }
  __syncthreads();
  if (threadIdx.x == 0) {
    if (atomicAdd(done, 1) == gridDim.x - 1) {   // last block: build schedule
      int b = 0, pos = 0;
      for (int e = 0; e < NE; e++) {
        int c = atomicAdd(&cnt[e], 0);           // device-coherent read
        base[e] = b;
        int tiles = (c + 127) >> 7;
        for (int i = 0; i < tiles; i++) {
          int valid = c - i * 128; if (valid > 128) valid = 128;
          sched[pos++] = (e << 20) | (i << 8) | valid;
        }
        b += c;
      }
      base[NE] = b;
      *sched_n = pos;
    }
  }
}

// -------- fp32 -> bf16 conversion of BOTH weight tensors in one launch -----------------
// blocks [0, half): w1 -> w1_bf; [half, 2*half): w2 -> w2_bf. One dispatch saved.
__global__ __launch_bounds__(256) void cvt2_kernel(
    const float4* __restrict__ src1, ushort4* __restrict__ dst1,
    const float4* __restrict__ src2, ushort4* __restrict__ dst2, int half_blocks)
{
  int b = blockIdx.x;
  const float4* src = src1;
  ushort4* dst = dst1;
  if (b >= half_blocks) { b -= half_blocks; src = src2; dst = dst2; }
  const int i = b * 256 + threadIdx.x;
  float4 v = src[i];
  ushort4 o;
  o.x = f2bf(v.x); o.y = f2bf(v.y); o.z = f2bf(v.z); o.w = f2bf(v.w);
  dst[i] = o;
}

// -------- grouped GEMM: 128x128 tile, BK=64, single-buffer, 8 WAVES (512 thr) ---------
// R4's kernel verbatim (harness-validated): m97-style loop at 2x wave concurrency.
// Same grid (576), 32 KB LDS (cap 5 blocks/CU >= 2.25 resident), 18 waves/CU.
// Per-wave tile 64x32, acc[4][2]; staging/fragment/K order bitwise-identical to R0.
// GATHER=1: A rows gathered from x_bf via bucket (gemm1); GATHER=0: packed rows.
template <int RELU, int GATHER>
__global__ __launch_bounds__(512) void ffn_gemm(
    const unsigned short* __restrict__ A,     // GATHER ? x_bf [NTOK][DIM] : packed [NPAIR][DIM]
    const unsigned short* __restrict__ B,     // [NE][DIM][DIM]
    const float* __restrict__ bias,           // [NE][DIM]
    const int* __restrict__ base,
    const int* __restrict__ bucket,
    const int* __restrict__ sched, const int* __restrict__ sched_n,
    unsigned short* __restrict__ Out)         // packed
{
  const int l = blockIdx.x;
  const int xcd = l & 7;
  const int w = l >> 3;
  const int nt = w & 7;
  const int slot = xcd * 9 + (w >> 3);
  if (slot >= *sched_n) return;
  const int se = sched[slot];
  const int e = se >> 20;
  const int mt = (se >> 8) & 0xfff;
  const int valid = se & 255;               // valid rows in this tile (1..128)
  const int arow0 = base[e] + mt * 128;

  __shared__ unsigned short lda[128 * 64];  // 16 KB
  __shared__ unsigned short ldb[128 * 64];  // 16 KB (32 KB total -> 5 blocks/CU cap)

  const int tid = threadIdx.x;
  const int lane = tid & 63;
  const int wid = tid >> 6;                 // 0..7

  const unsigned short* ap[2];
  const unsigned short* bp[2];
#pragma unroll
  for (int j = 0; j < 2; j++) {
    int g = wid * 2 + j;                    // 16 groups x 8 rows = 128 rows
    int row = g * 8 + (lane >> 3);
    int gran = (lane & 7) ^ (row & 7);      // source-side XOR swizzle (0 conflicts)
    if (GATHER) {
      int idx = mt * 128 + row;             // within-expert index
      int ce = base[e + 1] - base[e];       // expert count (>=1 if tile exists)
      if (idx > ce - 1) idx = ce - 1;       // clamp pad rows (masked at store)
      int tok = bucket[e * NTOK + idx] >> 1;
      ap[j] = A + (size_t)tok * DIM + (gran << 3);
    } else {
      int prow = arow0 + row;
      if (prow > NPAIR - 1) prow = NPAIR - 1;
      ap[j] = A + (size_t)prow * DIM + (gran << 3);
    }
    bp[j] = B + ((size_t)e * DIM + nt * 128 + row) * DIM + (gran << 3);
  }

  floatx4 acc[4][2] = {};
  const int wm = (wid & 1) * 64;            // 2 m-waves x 64 rows
  const int wn = (wid >> 1) * 32;           // 4 n-waves x 32 cols
  const int quad = lane >> 4;
  const int cl = lane & 15;
  const int sw = cl & 7;

  for (int k0 = 0; k0 < 16; k0++) {
#pragma unroll
    for (int j = 0; j < 2; j++) {
      gld_lds16(ap[j], &lda[(wid * 2 + j) * 512]);
      gld_lds16(bp[j], &ldb[(wid * 2 + j) * 512]);
      ap[j] += 64;
      bp[j] += 64;
    }
    __syncthreads();
#pragma unroll
    for (int kk = 0; kk < 64; kk += 32) {
      const int gb = (kk >> 3) + quad;
      const int goff = ((gb ^ sw) << 3);
      bf16x8 af[4], bfr[2];
#pragma unroll
      for (int mi = 0; mi < 4; mi++)
        af[mi] = *(const bf16x8*)&lda[(wm + mi * 16 + cl) * 64 + goff];
#pragma unroll
      for (int ni = 0; ni < 2; ni++)
        bfr[ni] = *(const bf16x8*)&ldb[(wn + ni * 16 + cl) * 64 + goff];
#pragma unroll
      for (int mi = 0; mi < 4; mi++)
#pragma unroll
        for (int ni = 0; ni < 2; ni++)
          acc[mi][ni] = __builtin_amdgcn_mfma_f32_16x16x32_bf16(af[mi], bfr[ni], acc[mi][ni], 0, 0, 0);
    }
    if (k0 < 15) __syncthreads();
  }

  // epilogue: C/D layout col=lane&15, row=(lane>>4)*4+reg [m89]; sequential packed store
#pragma unroll
  for (int ni = 0; ni < 2; ni++) {
    int col = nt * 128 + wn + ni * 16 + cl;
    float bval = bias[e * DIM + col];
#pragma unroll
    for (int mi = 0; mi < 4; mi++) {
#pragma unroll
      for (int reg = 0; reg < 4; reg++) {
        int rl = wm + mi * 16 + quad * 4 + reg;
        if (rl < valid) {
          float v = acc[mi][ni][reg] + bval;
          if (RELU) v = fmaxf(v, 0.f);
          Out[(size_t)(arow0 + rl) * DIM + col] = f2bf(v);
        }
      }
    }
  }
}

// ---------------- combine: y[t] = w0*o[p0] + w1*o[p1] (gather via posmap) --------------
__global__ __launch_bounds__(256) void combine_kernel(
    const unsigned short* __restrict__ o, const int* __restrict__ posmap,
    const int* __restrict__ base, const float* __restrict__ pairw,
    float* __restrict__ y)
{
  const int t = blockIdx.x;
  const int tid = threadIdx.x;
  const int pm0 = posmap[t * 2], pm1 = posmap[t * 2 + 1];
  const int p0 = base[pm0 >> 16] + (pm0 & 0xffff);
  const int p1 = base[pm1 >> 16] + (pm1 & 0xffff);
  const float w0 = pairw[t * 2], w1 = pairw[t * 2 + 1];
  ushort4 a = ((const ushort4*)(o + (size_t)p0 * DIM))[tid];
  ushort4 b = ((const ushort4*)(o + (size_t)p1 * DIM))[tid];
  float4 r;
  r.x = w0 * bf2f(a.x) + w1 * bf2f(b.x);
  r.y = w0 * bf2f(a.y) + w1 * bf2f(b.y);
  r.z = w0 * bf2f(a.z) + w1 * bf2f(b.z);
  r.w = w0 * bf2f(a.w) + w1 * bf2f(b.w);
  ((float4*)(y + (size_t)t * DIM))[tid] = r;
}

extern "C" void kernel_launch(void* const* d_in, const int* in_sizes, int n_in,
                              void* d_out, int out_size, void* d_ws, size_t ws_size,
                              hipStream_t stream) {
  const float* x  = (const float*)d_in[0];
  const float* gW = (const float*)d_in[1];
  const float* gb = (const float*)d_in[2];
  const float* w1 = (const float*)d_in[3];
  const float* b1 = (const float*)d_in[4];
  const float* w2 = (const float*)d_in[5];
  const float* b2 = (const float*)d_in[6];
  float* y  = (float*)d_out;
  float* gp = (float*)d_out + (size_t)NTOK * DIM;

  // ws layout (bytes) — peak 56M + ~230K, inside the 56.4M envelope validated in the
  // prior session. De-aliased w2_bf so BOTH weights convert in ONE launch before gemm1:
  //  [0,8M):    x_bf (gate->gemm1)
  //  [8,24M):   w2_bf (cvt->gemm2)
  //  [24,40M):  h_pack (gemm1 out -> gemm2 A)
  //  [40,56M):  w1_bf (cvt->gemm1 B) -> dead after gemm1 -> o_pack (gemm2 out)
  //  [56M,..):  cnt|done|base|sched|sched_n|bucket|pairw|tops|posmap
  char* ws = (char*)d_ws;
  unsigned short* x_bf   = (unsigned short*)(ws);
  unsigned short* w2_bf  = (unsigned short*)(ws + (size_t)(8u << 20));
  unsigned short* h_pack = (unsigned short*)(ws + (size_t)(24u << 20));
  unsigned short* w1_bf  = (unsigned short*)(ws + (size_t)(40u << 20));
  unsigned short* o_pack = (unsigned short*)(ws + (size_t)(40u << 20)); // alias, post-gemm1
  char* tail = ws + (size_t)(56u << 20);
  int*   cnt     = (int*)(tail);                   // 8
  int*   done    = cnt + NE;                       // 1
  int*   base    = done + 1;                       // 9
  int*   sched   = base + NE + 1;                  // <=256 (128-row tiles: up to 72)
  int*   sched_n = sched + 256;                    // 1
  int*   bucket  = sched_n + 1;                    // NE*NTOK
  float* pairw   = (float*)(bucket + NE * NTOK);   // NPAIR
  int2*  tops    = (int2*)(pairw + NPAIR);         // NTOK
  int*   posmap  = (int*)(tops + NTOK);            // NPAIR

  const int cvt_half = (NE * DIM * DIM / 4) / 256;    // 8192 blocks per tensor
  const int gemm_grid = 576;                           // 8 xcd x 9 slots x 8 nt
  cvt2_kernel<<<cvt_half * 2, 256, 0, stream>>>((const float4*)w1, (ushort4*)w1_bf,
                                                (const float4*)w2, (ushort4*)w2_bf, cvt_half);
  gate_kernel<<<NTOK / 4, 256, 0, stream>>>(x, gW, gb, gp, tops, pairw, cnt, done, x_bf);
  bin_sched_kernel<<<NTOK / 256, 256, 0, stream>>>(tops, cnt, bucket, posmap, done,
                                                   base, sched, sched_n);
  ffn_gemm<1, 1><<<gemm_grid, 512, 0, stream>>>(x_bf, w1_bf, b1, base, bucket, sched, sched_n, h_pack);
  ffn_gemm<0, 0><<<gemm_grid, 512, 0, stream>>>(h_pack, w2_bf, b2, base, bucket, sched, sched_n, o_pack);
  combine_kernel<<<NTOK, 256, 0, stream>>>(o_pack, posmap, base, pairw, y);
}